// Round 5
// baseline (1406.984 us; speedup 1.0000x reference)
//
#include <hip/hip_runtime.h>
#include <hip/hip_fp16.h>

// Persistent fused GRU + value head, MI355X (gfx950).
// T=512,B=256,I=64,H=512. 256 blocks = 16 batch groups x 16 hidden slices.
// R18 = R13 champion VERBATIM (protocol, poll, load-asm with INTERNAL
// vmcnt(0), single 16-step MFMA chain, identical FP order) + ONE change:
//   x-GEMM (2 LDS reads + 6 MFMAs) hoisted BEFORE the flag poll, pinned by
//   sched_barrier(0). Peer-independent work runs in the dead window while
//   our t-1 flag propagates to MALL and peers' flags become visible.
// HARD RULE (R15/R17 post-mortem): at this register pressure (~176 VGPR,
// wh[] alone ~192 VGPR-equiv) every VMEM asm block must contain its own
// s_waitcnt. Decoupling issue from wait lets the allocator copy/spill
// in-flight destination VGPRs before the load lands -> silent corruption.

#define T_  512
#define B_  256
#define I_  64
#define H_  512
#define NBG 16
#define BT  16                  // batch rows per group
#define HS  32                  // hidden units per block
#define BLOCK 192
#define NSL 32                  // value-head slices (j,wv)

typedef _Float16 f16;
typedef _Float16 f16x8 __attribute__((ext_vector_type(8)));
typedef float    f32x4 __attribute__((ext_vector_type(4)));
typedef unsigned int u32x2 __attribute__((ext_vector_type(2)));

__device__ __forceinline__ float sigmoid_f(float x) { return 1.f / (1.f + __expf(-x)); }
__device__ __forceinline__ float tanh_f(float x) {
    float e2 = __expf(2.f * x);
    return 1.f - 2.f / (e2 + 1.f);
}

__global__ __launch_bounds__(BLOCK, 1) void gru_persistent(
    const float* __restrict__ X, const float* __restrict__ Wih,
    const float* __restrict__ Whh, const float* __restrict__ bih,
    const float* __restrict__ bhh, const float* __restrict__ vw,
    const float* __restrict__ bias, float* __restrict__ Vout,
    f16* __restrict__ hbuf, unsigned int* __restrict__ flags,
    float* __restrict__ part, const int use_part)
{
    const int blk  = blockIdx.x;
    const int g    = (blk & 7) * 2 + (blk >> 7);   // group members share blk%8
    const int j    = (blk >> 3) & 15;
    const int b0   = g * BT;
    const int tid  = threadIdx.x;
    const int wv   = tid >> 6;
    const int lane = tid & 63;
    const int quad = lane >> 4;
    const int mrow = lane & 15;

    __shared__ __align__(16) f16 sh_x[2][BT][I_ + 8];   // X_t ping-pong (f16), padded
    unsigned int* gflags = flags + (size_t)g * 32;       // one 128B line per group

    if (wv < 2) {
        // ============ MFMA waves: weights=A (units on M), h/x=B (batch on N) ============
        // A[m=lane&15 -> unit][k=quad*8+e]; D: row=quad*4+r -> unit, col=lane&15 -> batch
        f16x8 wh[3][16];
        f16x8 wxA[3][2];
        const int um = HS * j + wv * 16 + mrow;
        #pragma unroll
        for (int g3 = 0; g3 < 3; g3++) {
            const size_t grow = (size_t)(g3 * H_ + um);
            #pragma unroll
            for (int kt = 0; kt < 16; kt++) {
                const float* src = Whh + grow * H_ + kt * 32 + quad * 8;
                #pragma unroll
                for (int e = 0; e < 8; e++) wh[g3][kt][e] = (f16)src[e];
            }
            #pragma unroll
            for (int kt = 0; kt < 2; kt++) {
                const float* src = Wih + grow * I_ + kt * 32 + quad * 8;
                #pragma unroll
                for (int e = 0; e < 8; e++) wxA[g3][kt][e] = (f16)src[e];
            }
        }
        float b_r4[4], b_z4[4], b_ni4[4], b_nh4[4], vw4[4];
        #pragma unroll
        for (int r = 0; r < 4; r++) {
            const int ub = HS * j + wv * 16 + quad * 4 + r;
            b_r4[r]  = bih[ub] + bhh[ub];
            b_z4[r]  = bih[H_ + ub] + bhh[H_ + ub];
            b_ni4[r] = bih[2 * H_ + ub];
            b_nh4[r] = bhh[2 * H_ + ub];
            vw4[r]   = vw[ub];
        }
        float hprev[4] = {0.f, 0.f, 0.f, 0.f};   // fp32 anchor for z*h (t=0 zeros)
        unsigned int* myflag = gflags + (j * 2 + wv);
        const int sl = j * 2 + wv;
        const float bias0 = bias[0];

        __syncthreads();   // init: service staged X_0 into slot 0

        #pragma unroll 1
        for (int t = 0; t < T_; t++) {
            // ---- 0. x-GEMM hoisted: peer-independent; runs in the dead window
            //         while our t-1 flag propagates and peers' flags surface.
            //         (sh_x[t&1] was written in iter t-1, fenced by barrier.) ----
            f16x8 bx0 = *(const f16x8*)&sh_x[t & 1][mrow][quad * 8];
            f16x8 bx1 = *(const f16x8*)&sh_x[t & 1][mrow][32 + quad * 8];
            const f32x4 zero = {0.f, 0.f, 0.f, 0.f};
            f32x4 a_r  = __builtin_amdgcn_mfma_f32_16x16x32_f16(wxA[0][0], bx0, zero, 0, 0, 0);
            f32x4 a_z  = __builtin_amdgcn_mfma_f32_16x16x32_f16(wxA[1][0], bx0, zero, 0, 0, 0);
            f32x4 a_ni = __builtin_amdgcn_mfma_f32_16x16x32_f16(wxA[2][0], bx0, zero, 0, 0, 0);
            a_r  = __builtin_amdgcn_mfma_f32_16x16x32_f16(wxA[0][1], bx1, a_r,  0, 0, 0);
            a_z  = __builtin_amdgcn_mfma_f32_16x16x32_f16(wxA[1][1], bx1, a_z,  0, 0, 0);
            a_ni = __builtin_amdgcn_mfma_f32_16x16x32_f16(wxA[2][1], bx1, a_ni, 0, 0, 0);
            __builtin_amdgcn_sched_barrier(0);   // pin x-GEMM above the poll

            // ---- 1. ballot poll: one coalesced 128B line read per iteration
            //         (champion-exact: wait INSIDE the asm block) ----
            if (t > 0) {
                const unsigned target = (unsigned)t;
                for (;;) {
                    unsigned v = target;
                    if (lane < 32) {
                        const unsigned int* fp = gflags + lane;
                        asm volatile("global_load_dword %0, %1, off sc0 sc1\n\t"
                                     "s_waitcnt vmcnt(0)"
                                     : "=v"(v) : "v"(fp) : "memory");
                    }
                    if (__ballot(v >= target) == ~0ull) break;
                }
            }

            // ---- 2. h_{t-1} fragments: fragment-major slab, 16 x 1KB-contiguous
            //         loads, vmcnt(0) INSIDE the asm (hard rule) ----
            f16x8 afr[16];
            const char* pb = (const char*)(hbuf
                           + ((size_t)((t & 1) ^ 1) * NBG + g) * 8192)
                           + quad * 256 + mrow * 16;
            asm volatile(
                "global_load_dwordx4 %0, %16, off sc0 sc1\n\t"
                "global_load_dwordx4 %1, %16, off offset:1024 sc0 sc1\n\t"
                "global_load_dwordx4 %2, %16, off offset:2048 sc0 sc1\n\t"
                "global_load_dwordx4 %3, %16, off offset:3072 sc0 sc1\n\t"
                "global_load_dwordx4 %4, %17, off sc0 sc1\n\t"
                "global_load_dwordx4 %5, %17, off offset:1024 sc0 sc1\n\t"
                "global_load_dwordx4 %6, %17, off offset:2048 sc0 sc1\n\t"
                "global_load_dwordx4 %7, %17, off offset:3072 sc0 sc1\n\t"
                "global_load_dwordx4 %8, %18, off sc0 sc1\n\t"
                "global_load_dwordx4 %9, %18, off offset:1024 sc0 sc1\n\t"
                "global_load_dwordx4 %10, %18, off offset:2048 sc0 sc1\n\t"
                "global_load_dwordx4 %11, %18, off offset:3072 sc0 sc1\n\t"
                "global_load_dwordx4 %12, %19, off sc0 sc1\n\t"
                "global_load_dwordx4 %13, %19, off offset:1024 sc0 sc1\n\t"
                "global_load_dwordx4 %14, %19, off offset:2048 sc0 sc1\n\t"
                "global_load_dwordx4 %15, %19, off offset:3072 sc0 sc1\n\t"
                "s_waitcnt vmcnt(0)"
                : "=&v"(afr[0]), "=&v"(afr[1]), "=&v"(afr[2]), "=&v"(afr[3]),
                  "=&v"(afr[4]), "=&v"(afr[5]), "=&v"(afr[6]), "=&v"(afr[7]),
                  "=&v"(afr[8]), "=&v"(afr[9]), "=&v"(afr[10]), "=&v"(afr[11]),
                  "=&v"(afr[12]), "=&v"(afr[13]), "=&v"(afr[14]), "=&v"(afr[15])
                : "v"(pb), "v"(pb + 4096), "v"(pb + 8192), "v"(pb + 12288)
                : "memory");

            // ---- 3. h-MFMA chain (champion-exact; x-MFMAs already folded in) ----
            f32x4 a_nh = zero;
            #pragma unroll
            for (int kt = 0; kt < 16; kt++) {
                a_r  = __builtin_amdgcn_mfma_f32_16x16x32_f16(wh[0][kt], afr[kt], a_r,  0, 0, 0);
                a_z  = __builtin_amdgcn_mfma_f32_16x16x32_f16(wh[1][kt], afr[kt], a_z,  0, 0, 0);
                a_nh = __builtin_amdgcn_mfma_f32_16x16x32_f16(wh[2][kt], afr[kt], a_nh, 0, 0, 0);
            }

            // ---- 4. gates in registers; one 8B fragment-major h-store/lane ----
            float hn[4];
            union { f16 h[4]; u32x2 v; } pk;
            #pragma unroll
            for (int r = 0; r < 4; r++) {
                float rg = sigmoid_f(a_r[r] + b_r4[r]);
                float zg = sigmoid_f(a_z[r] + b_z4[r]);
                float ng = tanh_f(a_ni[r] + b_ni4[r] + rg * (a_nh[r] + b_nh4[r]));
                hn[r] = (1.f - zg) * ng + zg * hprev[r];
                hprev[r] = hn[r];
                pk.h[r] = (f16)hn[r];
            }
            {
                // h[batch=mrow][u=32j+16wv+4quad+r] -> idx=(u>>3)*128 + mrow*8 + (u&7)
                f16* hp = hbuf + ((size_t)(t & 1) * NBG + g) * 8192
                        + (size_t)((4 * j + 2 * wv + (quad >> 1)) * 128
                                   + mrow * 8 + (quad & 1) * 4);
                asm volatile("global_store_dwordx2 %0, %1, off sc0 sc1"
                             :: "v"(hp), "v"(pk.v) : "memory");
            }
            // value-head partial overlaps the store's flight time
            float s = hn[0] * vw4[0] + hn[1] * vw4[1] + hn[2] * vw4[2] + hn[3] * vw4[3];
            s += __shfl_xor(s, 16);
            s += __shfl_xor(s, 32);

            asm volatile("s_waitcnt vmcnt(0)" ::: "memory");   // h at MALL before flag
            if (lane == 0)
                __hip_atomic_store(myflag, (unsigned)(t + 1),
                                   __ATOMIC_RELAXED, __HIP_MEMORY_SCOPE_AGENT);
            if (quad == 0) {
                if (use_part) part[(size_t)sl * (T_ * B_) + (size_t)t * B_ + b0 + mrow] = s;
                else atomicAdd(&Vout[(size_t)t * B_ + b0 + mrow], s + (sl == 0 ? bias0 : 0.f));
            }
            __syncthreads();   // X ping-pong fence with service wave (off exchange path)
        }
    } else {
        // ============== service wave: X_{t+1} -> LDS ping-pong (off-path) ==============
        const int bb = lane >> 2, seg = (lane & 3) * 16;
        {   // stage X_0 -> slot 0
            const float* xs = X + (size_t)(b0 + bb) * I_ + seg;
            const float4 x0 = *(const float4*)(xs + 0),  x1 = *(const float4*)(xs + 4);
            const float4 x2 = *(const float4*)(xs + 8),  x3 = *(const float4*)(xs + 12);
            f16* dst = &sh_x[0][bb][seg];
            f16x8 p0 = {(f16)x0.x,(f16)x0.y,(f16)x0.z,(f16)x0.w,(f16)x1.x,(f16)x1.y,(f16)x1.z,(f16)x1.w};
            f16x8 p1 = {(f16)x2.x,(f16)x2.y,(f16)x2.z,(f16)x2.w,(f16)x3.x,(f16)x3.y,(f16)x3.z,(f16)x3.w};
            *(f16x8*)dst = p0; *(f16x8*)(dst + 8) = p1;
        }
        __syncthreads();   // init barrier
        #pragma unroll 1
        for (int t = 0; t < T_; t++) {
            if (t + 1 < T_) {
                const float* xs = X + (size_t)(t + 1) * (B_ * I_) + (size_t)(b0 + bb) * I_ + seg;
                const float4 x0 = *(const float4*)(xs + 0),  x1 = *(const float4*)(xs + 4);
                const float4 x2 = *(const float4*)(xs + 8),  x3 = *(const float4*)(xs + 12);
                f16* dst = &sh_x[(t + 1) & 1][bb][seg];
                f16x8 p0 = {(f16)x0.x,(f16)x0.y,(f16)x0.z,(f16)x0.w,(f16)x1.x,(f16)x1.y,(f16)x1.z,(f16)x1.w};
                f16x8 p1 = {(f16)x2.x,(f16)x2.y,(f16)x2.z,(f16)x2.w,(f16)x3.x,(f16)x3.y,(f16)x3.z,(f16)x3.w};
                *(f16x8*)dst = p0; *(f16x8*)(dst + 8) = p1;
            }
            __syncthreads();
        }
    }
}

__global__ __launch_bounds__(256) void value_reduce(
    const float* __restrict__ part, const float* __restrict__ bias,
    float* __restrict__ Vout)
{
    const int i = blockIdx.x * 256 + threadIdx.x;   // i < T_*B_
    float s = bias[0];
    #pragma unroll
    for (int sl = 0; sl < NSL; sl++) s += part[(size_t)sl * (T_ * B_) + i];
    Vout[i] = s;
}

extern "C" void kernel_launch(void* const* d_in, const int* in_sizes, int n_in,
                              void* d_out, int out_size, void* d_ws, size_t ws_size,
                              hipStream_t stream) {
    const float* X    = (const float*)d_in[0];
    const float* Wih  = (const float*)d_in[1];
    const float* Whh  = (const float*)d_in[2];
    const float* bih  = (const float*)d_in[3];
    const float* bhh  = (const float*)d_in[4];
    const float* vw   = (const float*)d_in[5];
    const float* bias = (const float*)d_in[6];
    float* Vout = (float*)d_out;

    f16* hbuf = (f16*)d_ws;
    const size_t hbytes    = (size_t)2 * B_ * H_ * sizeof(f16);        // 512 KB
    const size_t flagbytes = (size_t)NBG * 32 * sizeof(unsigned);      // 2 KB (1 line/group)
    unsigned int* flags = (unsigned int*)((char*)d_ws + hbytes);
    float* part = (float*)((char*)d_ws + hbytes + flagbytes);
    const size_t partbytes = (size_t)NSL * T_ * B_ * sizeof(float);    // 16.8 MB
    const int use_part = (ws_size >= hbytes + flagbytes + partbytes) ? 1 : 0;

    hipMemsetAsync(d_ws, 0, hbytes + flagbytes, stream);   // hbuf zeros (t=0) + flags
    if (!use_part)
        hipMemsetAsync(d_out, 0, (size_t)out_size * sizeof(float), stream);

    gru_persistent<<<256, BLOCK, 0, stream>>>(X, Wih, Whh, bih, bhh, vw, bias,
                                              Vout, hbuf, flags, part, use_part);
    if (use_part)
        value_reduce<<<(T_ * B_) / 256, 256, 0, stream>>>(part, bias, Vout);
}

// Round 6
// 1384.138 us; speedup vs baseline: 1.0165x; 1.0165x over previous
//
#include <hip/hip_runtime.h>
#include <hip/hip_fp16.h>

// Persistent fused GRU + value head, MI355X (gfx950).
// T=512,B=256,I=64,H=512. 256 blocks = 16 batch groups x 16 hidden slices.
// R19 = R18 (champion protocol; x-GEMM hoisted) with the iteration TAIL
// reordered to hide the h-store ack (vmcnt(0)) under flag-independent work:
//   old: gates -> h-store -> vh -> ACK -> flag -> part -> barrier | xGEMM -> poll
//   new: gates -> h-store -> vh -> barrier -> xGEMM(t+1) -> ACK -> flag -> part -> poll
// The barrier (service wave long done) + next-step x-GEMM (~350cy) overlap
// the MALL write round trip, so the ack is mostly drained when we wait.
// Flag still strictly follows ack -> protocol unchanged. FP order identical.
// HARD RULE (R15/R17 post-mortem): every VMEM asm block contains its own
// s_waitcnt — decoupling issue from wait lets the allocator touch in-flight
// destination VGPRs -> silent corruption at this register pressure.

#define T_  512
#define B_  256
#define I_  64
#define H_  512
#define NBG 16
#define BT  16                  // batch rows per group
#define HS  32                  // hidden units per block
#define BLOCK 192
#define NSL 32                  // value-head slices (j,wv)

typedef _Float16 f16;
typedef _Float16 f16x8 __attribute__((ext_vector_type(8)));
typedef float    f32x4 __attribute__((ext_vector_type(4)));
typedef unsigned int u32x2 __attribute__((ext_vector_type(2)));

__device__ __forceinline__ float sigmoid_f(float x) { return 1.f / (1.f + __expf(-x)); }
__device__ __forceinline__ float tanh_f(float x) {
    float e2 = __expf(2.f * x);
    return 1.f - 2.f / (e2 + 1.f);
}

__global__ __launch_bounds__(BLOCK, 1) void gru_persistent(
    const float* __restrict__ X, const float* __restrict__ Wih,
    const float* __restrict__ Whh, const float* __restrict__ bih,
    const float* __restrict__ bhh, const float* __restrict__ vw,
    const float* __restrict__ bias, float* __restrict__ Vout,
    f16* __restrict__ hbuf, unsigned int* __restrict__ flags,
    float* __restrict__ part, const int use_part)
{
    const int blk  = blockIdx.x;
    const int g    = (blk & 7) * 2 + (blk >> 7);   // group members share blk%8
    const int j    = (blk >> 3) & 15;
    const int b0   = g * BT;
    const int tid  = threadIdx.x;
    const int wv   = tid >> 6;
    const int lane = tid & 63;
    const int quad = lane >> 4;
    const int mrow = lane & 15;

    __shared__ __align__(16) f16 sh_x[2][BT][I_ + 8];   // X_t ping-pong (f16), padded
    unsigned int* gflags = flags + (size_t)g * 32;       // one 128B line per group

    if (wv < 2) {
        // ============ MFMA waves: weights=A (units on M), h/x=B (batch on N) ============
        // A[m=lane&15 -> unit][k=quad*8+e]; D: row=quad*4+r -> unit, col=lane&15 -> batch
        f16x8 wh[3][16];
        f16x8 wxA[3][2];
        const int um = HS * j + wv * 16 + mrow;
        #pragma unroll
        for (int g3 = 0; g3 < 3; g3++) {
            const size_t grow = (size_t)(g3 * H_ + um);
            #pragma unroll
            for (int kt = 0; kt < 16; kt++) {
                const float* src = Whh + grow * H_ + kt * 32 + quad * 8;
                #pragma unroll
                for (int e = 0; e < 8; e++) wh[g3][kt][e] = (f16)src[e];
            }
            #pragma unroll
            for (int kt = 0; kt < 2; kt++) {
                const float* src = Wih + grow * I_ + kt * 32 + quad * 8;
                #pragma unroll
                for (int e = 0; e < 8; e++) wxA[g3][kt][e] = (f16)src[e];
            }
        }
        float b_r4[4], b_z4[4], b_ni4[4], b_nh4[4], vw4[4];
        #pragma unroll
        for (int r = 0; r < 4; r++) {
            const int ub = HS * j + wv * 16 + quad * 4 + r;
            b_r4[r]  = bih[ub] + bhh[ub];
            b_z4[r]  = bih[H_ + ub] + bhh[H_ + ub];
            b_ni4[r] = bih[2 * H_ + ub];
            b_nh4[r] = bhh[2 * H_ + ub];
            vw4[r]   = vw[ub];
        }
        float hprev[4] = {0.f, 0.f, 0.f, 0.f};   // fp32 anchor for z*h (t=0 zeros)
        unsigned int* myflag = gflags + (j * 2 + wv);
        const int sl = j * 2 + wv;
        const float bias0 = bias[0];
        const f32x4 zero = {0.f, 0.f, 0.f, 0.f};

        __syncthreads();   // init: service staged X_0 into slot 0

        // ---- x-GEMM for t=0 (slot 0), loop-carried into the first iteration ----
        f32x4 xr, xz, xni;
        {
            f16x8 bx0 = *(const f16x8*)&sh_x[0][mrow][quad * 8];
            f16x8 bx1 = *(const f16x8*)&sh_x[0][mrow][32 + quad * 8];
            xr  = __builtin_amdgcn_mfma_f32_16x16x32_f16(wxA[0][0], bx0, zero, 0, 0, 0);
            xz  = __builtin_amdgcn_mfma_f32_16x16x32_f16(wxA[1][0], bx0, zero, 0, 0, 0);
            xni = __builtin_amdgcn_mfma_f32_16x16x32_f16(wxA[2][0], bx0, zero, 0, 0, 0);
            xr  = __builtin_amdgcn_mfma_f32_16x16x32_f16(wxA[0][1], bx1, xr,  0, 0, 0);
            xz  = __builtin_amdgcn_mfma_f32_16x16x32_f16(wxA[1][1], bx1, xz,  0, 0, 0);
            xni = __builtin_amdgcn_mfma_f32_16x16x32_f16(wxA[2][1], bx1, xni, 0, 0, 0);
        }

        #pragma unroll 1
        for (int t = 0; t < T_; t++) {
            // ---- 1. ballot poll: one coalesced 128B line read per iteration
            //         (champion-exact: wait INSIDE the asm block) ----
            if (t > 0) {
                const unsigned target = (unsigned)t;
                for (;;) {
                    unsigned v = target;
                    if (lane < 32) {
                        const unsigned int* fp = gflags + lane;
                        asm volatile("global_load_dword %0, %1, off sc0 sc1\n\t"
                                     "s_waitcnt vmcnt(0)"
                                     : "=v"(v) : "v"(fp) : "memory");
                    }
                    if (__ballot(v >= target) == ~0ull) break;
                }
            }

            // ---- 2. h_{t-1} fragments: fragment-major slab, 16 x 1KB-contiguous
            //         loads, vmcnt(0) INSIDE the asm (hard rule) ----
            f16x8 afr[16];
            const char* pb = (const char*)(hbuf
                           + ((size_t)((t & 1) ^ 1) * NBG + g) * 8192)
                           + quad * 256 + mrow * 16;
            asm volatile(
                "global_load_dwordx4 %0, %16, off sc0 sc1\n\t"
                "global_load_dwordx4 %1, %16, off offset:1024 sc0 sc1\n\t"
                "global_load_dwordx4 %2, %16, off offset:2048 sc0 sc1\n\t"
                "global_load_dwordx4 %3, %16, off offset:3072 sc0 sc1\n\t"
                "global_load_dwordx4 %4, %17, off sc0 sc1\n\t"
                "global_load_dwordx4 %5, %17, off offset:1024 sc0 sc1\n\t"
                "global_load_dwordx4 %6, %17, off offset:2048 sc0 sc1\n\t"
                "global_load_dwordx4 %7, %17, off offset:3072 sc0 sc1\n\t"
                "global_load_dwordx4 %8, %18, off sc0 sc1\n\t"
                "global_load_dwordx4 %9, %18, off offset:1024 sc0 sc1\n\t"
                "global_load_dwordx4 %10, %18, off offset:2048 sc0 sc1\n\t"
                "global_load_dwordx4 %11, %18, off offset:3072 sc0 sc1\n\t"
                "global_load_dwordx4 %12, %19, off sc0 sc1\n\t"
                "global_load_dwordx4 %13, %19, off offset:1024 sc0 sc1\n\t"
                "global_load_dwordx4 %14, %19, off offset:2048 sc0 sc1\n\t"
                "global_load_dwordx4 %15, %19, off offset:3072 sc0 sc1\n\t"
                "s_waitcnt vmcnt(0)"
                : "=&v"(afr[0]), "=&v"(afr[1]), "=&v"(afr[2]), "=&v"(afr[3]),
                  "=&v"(afr[4]), "=&v"(afr[5]), "=&v"(afr[6]), "=&v"(afr[7]),
                  "=&v"(afr[8]), "=&v"(afr[9]), "=&v"(afr[10]), "=&v"(afr[11]),
                  "=&v"(afr[12]), "=&v"(afr[13]), "=&v"(afr[14]), "=&v"(afr[15])
                : "v"(pb), "v"(pb + 4096), "v"(pb + 8192), "v"(pb + 12288)
                : "memory");

            // ---- 3. h-MFMA chain seeded by the loop-carried x-GEMM result ----
            f32x4 a_r = xr, a_z = xz, a_ni = xni;
            f32x4 a_nh = zero;
            #pragma unroll
            for (int kt = 0; kt < 16; kt++) {
                a_r  = __builtin_amdgcn_mfma_f32_16x16x32_f16(wh[0][kt], afr[kt], a_r,  0, 0, 0);
                a_z  = __builtin_amdgcn_mfma_f32_16x16x32_f16(wh[1][kt], afr[kt], a_z,  0, 0, 0);
                a_nh = __builtin_amdgcn_mfma_f32_16x16x32_f16(wh[2][kt], afr[kt], a_nh, 0, 0, 0);
            }

            // ---- 4. gates in registers; one 8B fragment-major h-store/lane ----
            float hn[4];
            union { f16 h[4]; u32x2 v; } pk;
            #pragma unroll
            for (int r = 0; r < 4; r++) {
                float rg = sigmoid_f(a_r[r] + b_r4[r]);
                float zg = sigmoid_f(a_z[r] + b_z4[r]);
                float ng = tanh_f(a_ni[r] + b_ni4[r] + rg * (a_nh[r] + b_nh4[r]));
                hn[r] = (1.f - zg) * ng + zg * hprev[r];
                hprev[r] = hn[r];
                pk.h[r] = (f16)hn[r];
            }
            {
                // h[batch=mrow][u=32j+16wv+4quad+r] -> idx=(u>>3)*128 + mrow*8 + (u&7)
                f16* hp = hbuf + ((size_t)(t & 1) * NBG + g) * 8192
                        + (size_t)((4 * j + 2 * wv + (quad >> 1)) * 128
                                   + mrow * 8 + (quad & 1) * 4);
                asm volatile("global_store_dwordx2 %0, %1, off sc0 sc1"
                             :: "v"(hp), "v"(pk.v) : "memory");
            }
            // value-head partial overlaps the store's flight time
            float s = hn[0] * vw4[0] + hn[1] * vw4[1] + hn[2] * vw4[2] + hn[3] * vw4[3];
            s += __shfl_xor(s, 16);
            s += __shfl_xor(s, 32);

            // ---- 5. barrier + next-step x-GEMM overlap the h-store drain ----
            __syncthreads();   // X ping-pong fence (service wave long done)
            if (t + 1 < T_) {
                f16x8 bx0 = *(const f16x8*)&sh_x[(t + 1) & 1][mrow][quad * 8];
                f16x8 bx1 = *(const f16x8*)&sh_x[(t + 1) & 1][mrow][32 + quad * 8];
                xr  = __builtin_amdgcn_mfma_f32_16x16x32_f16(wxA[0][0], bx0, zero, 0, 0, 0);
                xz  = __builtin_amdgcn_mfma_f32_16x16x32_f16(wxA[1][0], bx0, zero, 0, 0, 0);
                xni = __builtin_amdgcn_mfma_f32_16x16x32_f16(wxA[2][0], bx0, zero, 0, 0, 0);
                xr  = __builtin_amdgcn_mfma_f32_16x16x32_f16(wxA[0][1], bx1, xr,  0, 0, 0);
                xz  = __builtin_amdgcn_mfma_f32_16x16x32_f16(wxA[1][1], bx1, xz,  0, 0, 0);
                xni = __builtin_amdgcn_mfma_f32_16x16x32_f16(wxA[2][1], bx1, xni, 0, 0, 0);
            }
            __builtin_amdgcn_sched_barrier(0);   // pin x-GEMM before the ack

            // ---- 6. ack (mostly drained by now) -> flag -> part-store ----
            asm volatile("s_waitcnt vmcnt(0)" ::: "memory");   // h at MALL before flag
            if (lane == 0)
                __hip_atomic_store(myflag, (unsigned)(t + 1),
                                   __ATOMIC_RELAXED, __HIP_MEMORY_SCOPE_AGENT);
            if (quad == 0) {
                if (use_part) part[(size_t)sl * (T_ * B_) + (size_t)t * B_ + b0 + mrow] = s;
                else atomicAdd(&Vout[(size_t)t * B_ + b0 + mrow], s + (sl == 0 ? bias0 : 0.f));
            }
        }
    } else {
        // ============== service wave: X_{t+1} -> LDS ping-pong (off-path) ==============
        const int bb = lane >> 2, seg = (lane & 3) * 16;
        {   // stage X_0 -> slot 0
            const float* xs = X + (size_t)(b0 + bb) * I_ + seg;
            const float4 x0 = *(const float4*)(xs + 0),  x1 = *(const float4*)(xs + 4);
            const float4 x2 = *(const float4*)(xs + 8),  x3 = *(const float4*)(xs + 12);
            f16* dst = &sh_x[0][bb][seg];
            f16x8 p0 = {(f16)x0.x,(f16)x0.y,(f16)x0.z,(f16)x0.w,(f16)x1.x,(f16)x1.y,(f16)x1.z,(f16)x1.w};
            f16x8 p1 = {(f16)x2.x,(f16)x2.y,(f16)x2.z,(f16)x2.w,(f16)x3.x,(f16)x3.y,(f16)x3.z,(f16)x3.w};
            *(f16x8*)dst = p0; *(f16x8*)(dst + 8) = p1;
        }
        __syncthreads();   // init barrier
        #pragma unroll 1
        for (int t = 0; t < T_; t++) {
            if (t + 1 < T_) {
                const float* xs = X + (size_t)(t + 1) * (B_ * I_) + (size_t)(b0 + bb) * I_ + seg;
                const float4 x0 = *(const float4*)(xs + 0),  x1 = *(const float4*)(xs + 4);
                const float4 x2 = *(const float4*)(xs + 8),  x3 = *(const float4*)(xs + 12);
                f16* dst = &sh_x[(t + 1) & 1][bb][seg];
                f16x8 p0 = {(f16)x0.x,(f16)x0.y,(f16)x0.z,(f16)x0.w,(f16)x1.x,(f16)x1.y,(f16)x1.z,(f16)x1.w};
                f16x8 p1 = {(f16)x2.x,(f16)x2.y,(f16)x2.z,(f16)x2.w,(f16)x3.x,(f16)x3.y,(f16)x3.z,(f16)x3.w};
                *(f16x8*)dst = p0; *(f16x8*)(dst + 8) = p1;
            }
            __syncthreads();
        }
    }
}

__global__ __launch_bounds__(256) void value_reduce(
    const float* __restrict__ part, const float* __restrict__ bias,
    float* __restrict__ Vout)
{
    const int i = blockIdx.x * 256 + threadIdx.x;   // i < T_*B_
    float s = bias[0];
    #pragma unroll
    for (int sl = 0; sl < NSL; sl++) s += part[(size_t)sl * (T_ * B_) + i];
    Vout[i] = s;
}

extern "C" void kernel_launch(void* const* d_in, const int* in_sizes, int n_in,
                              void* d_out, int out_size, void* d_ws, size_t ws_size,
                              hipStream_t stream) {
    const float* X    = (const float*)d_in[0];
    const float* Wih  = (const float*)d_in[1];
    const float* Whh  = (const float*)d_in[2];
    const float* bih  = (const float*)d_in[3];
    const float* bhh  = (const float*)d_in[4];
    const float* vw   = (const float*)d_in[5];
    const float* bias = (const float*)d_in[6];
    float* Vout = (float*)d_out;

    f16* hbuf = (f16*)d_ws;
    const size_t hbytes    = (size_t)2 * B_ * H_ * sizeof(f16);        // 512 KB
    const size_t flagbytes = (size_t)NBG * 32 * sizeof(unsigned);      // 2 KB (1 line/group)
    unsigned int* flags = (unsigned int*)((char*)d_ws + hbytes);
    float* part = (float*)((char*)d_ws + hbytes + flagbytes);
    const size_t partbytes = (size_t)NSL * T_ * B_ * sizeof(float);    // 16.8 MB
    const int use_part = (ws_size >= hbytes + flagbytes + partbytes) ? 1 : 0;

    hipMemsetAsync(d_ws, 0, hbytes + flagbytes, stream);   // hbuf zeros (t=0) + flags
    if (!use_part)
        hipMemsetAsync(d_out, 0, (size_t)out_size * sizeof(float), stream);

    gru_persistent<<<256, BLOCK, 0, stream>>>(X, Wih, Whh, bih, bhh, vw, bias,
                                              Vout, hbuf, flags, part, use_part);
    if (use_part)
        value_reduce<<<(T_ * B_) / 256, 256, 0, stream>>>(part, bias, Vout);
}